// Round 11
// baseline (187.648 us; speedup 1.0000x reference)
//
#include <hip/hip_runtime.h>
#include <stdint.h>

#define NE 102400
#define DIM 256
#define NB 512
#define KROW (DIM / 4)   // 64 packed u32 per row
#define NTILE (NE / 128) // 800 entity tiles

#define SQ 384.0f
#define NINV (-1.0f / 384.0f)

#define XQ_BYTES ((size_t)NB * KROW * 4)        // 128 KiB
#define EQ_BYTES ((size_t)NE * KROW * 4)        // 25 MiB

typedef float vf4 __attribute__((ext_vector_type(4)));
typedef float vf2 __attribute__((ext_vector_type(2)));

#if __has_builtin(__builtin_amdgcn_sad_u8)
#define SAD(a, b, c) __builtin_amdgcn_sad_u8((a), (b), (c))
#else
static __device__ __forceinline__ uint32_t SAD(uint32_t a, uint32_t b,
                                               uint32_t c) {
  asm("v_sad_u8 %0, %1, %2, %0" : "+v"(c) : "v"(a), "v"(b));
  return c;
}
#endif

static __device__ __forceinline__ uint32_t quant4(float a, float b, float c,
                                                  float d) {
  uint32_t q = 0;
  asm("v_cvt_pk_u8_f32 %0, %1, 0, %0" : "+v"(q) : "v"(fmaf(a, SQ, 128.5f)));
  asm("v_cvt_pk_u8_f32 %0, %1, 1, %0" : "+v"(q) : "v"(fmaf(b, SQ, 128.5f)));
  asm("v_cvt_pk_u8_f32 %0, %1, 2, %0" : "+v"(q) : "v"(fmaf(c, SQ, 128.5f)));
  asm("v_cvt_pk_u8_f32 %0, %1, 3, %0" : "+v"(q) : "v"(fmaf(d, SQ, 128.5f)));
  return q;
}

// ---- pre-passes ---------------------------------------------------------

// xqT[k][b] = quantized (ent[h[b]] + rel[r[b]]) dims 4k..4k+3 (k-major).
__global__ __launch_bounds__(64) void make_xqT_kernel(
    const float* __restrict__ ent, const float* __restrict__ rel,
    const int* __restrict__ h_idx, const int* __restrict__ r_idx,
    uint32_t* __restrict__ xqT) {
  const int b = blockIdx.x;
  const int t = threadIdx.x;  // = k
  const float4 e = *(const float4*)&ent[(size_t)h_idx[b] * DIM + t * 4];
  const float4 r = *(const float4*)&rel[(size_t)r_idx[b] * DIM + t * 4];
  xqT[(size_t)t * NB + b] = quant4(e.x + r.x, e.y + r.y, e.z + r.z, e.w + r.w);
}

// eqT[tile][k][c] = quantized ent[tile*128+c] dims 4k..4k+3.
__global__ __launch_bounds__(256) void quant_entT_kernel(
    const float* __restrict__ ent, uint32_t* __restrict__ eqT) {
  const int t0 = blockIdx.x;
  const int r = threadIdx.x >> 1;       // entity row in tile
  const int h = threadIdx.x & 1;        // dim half
  const float* src = &ent[((size_t)t0 * 128 + r) * DIM + h * 128];
  uint32_t* dst = &eqT[(size_t)t0 * (KROW * 128) + (size_t)h * 32 * 128 + r];
#pragma unroll
  for (int q = 0; q < 32; ++q) {
    const float4 v = *(const float4*)&src[q * 4];
    dst[q * 128] = quant4(v.x, v.y, v.z, v.w);
  }
}

// ---- main kernel --------------------------------------------------------
// out[b][n] = -sum_d |x[b][d] - ent[n][d]| via u8 SAD.
// 512 threads = 8 waves, no LDS. Wave w: 32 uniform batch rows (x via
// scalar loads, SGPR src) x 128 entity cols (lane l: cols 2l,2l+1 via
// global_load_dwordx2 from L2-resident eqT, prefetched one k ahead).
__global__ __launch_bounds__(512, 2) void transe_sad_sgpr_kernel(
    const uint32_t* __restrict__ eqT, const uint32_t* __restrict__ xqT,
    float* __restrict__ out) {
  const int tid = threadIdx.x;
  const int lane = tid & 63;
  const int wid = __builtin_amdgcn_readfirstlane(tid >> 6);  // 0..7, uniform
  const int n0 = blockIdx.x * 128;
  const int brow = blockIdx.y * 256 + wid * 32;              // uniform

  const uint32_t* ebase =
      eqT + (size_t)blockIdx.x * (KROW * 128) + lane * 2;
  const uint32_t* xrow = xqT + brow;  // uniform pointer

  uint32_t acc[32][2];
#pragma unroll
  for (int i = 0; i < 32; ++i) {
    acc[i][0] = 0u;
    acc[i][1] = 0u;
  }

  uint2 ev = *(const uint2*)&ebase[0];  // prefetch k=0

#pragma unroll 2
  for (int k = 0; k < KROW - 1; ++k) {
    const uint2 evn = *(const uint2*)&ebase[(k + 1) * 128];  // prefetch k+1
    const uint32_t* xp = xrow + (size_t)k * NB;              // uniform
#pragma unroll
    for (int i = 0; i < 32; ++i) {
      const uint32_t sx = xp[i];  // uniform -> s_load (SGPR src0)
      acc[i][0] = SAD(sx, ev.x, acc[i][0]);
      acc[i][1] = SAD(sx, ev.y, acc[i][1]);
    }
    ev = evn;
  }
  {  // k = KROW-1 (no prefetch past end)
    const uint32_t* xp = xrow + (size_t)(KROW - 1) * NB;
#pragma unroll
    for (int i = 0; i < 32; ++i) {
      const uint32_t sx = xp[i];
      acc[i][0] = SAD(sx, ev.x, acc[i][0]);
      acc[i][1] = SAD(sx, ev.y, acc[i][1]);
    }
  }

  // ---- epilogue: out = -acc/384, non-temporal float2 stores ----
#pragma unroll
  for (int i = 0; i < 32; ++i) {
    float* dst = &out[(size_t)(brow + i) * NE + n0 + lane * 2];
    vf2 o;
    o.x = (float)acc[i][0] * NINV;
    o.y = (float)acc[i][1] * NINV;
    __builtin_nontemporal_store(o, (vf2*)dst);
  }
}

// ---- fallback path (ws too small): row-major xq + in-kernel e-quant ----

__global__ __launch_bounds__(64) void make_xq_kernel(
    const float* __restrict__ ent, const float* __restrict__ rel,
    const int* __restrict__ h_idx, const int* __restrict__ r_idx,
    uint32_t* __restrict__ xq) {
  const int b = blockIdx.x;
  const int t = threadIdx.x;
  const float4 e = *(const float4*)&ent[(size_t)h_idx[b] * DIM + t * 4];
  const float4 r = *(const float4*)&rel[(size_t)r_idx[b] * DIM + t * 4];
  xq[(size_t)b * KROW + t] = quant4(e.x + r.x, e.y + r.y, e.z + r.z, e.w + r.w);
}

__global__ __launch_bounds__(256) void transe_sad_f32_kernel(
    const float* __restrict__ ent, const uint32_t* __restrict__ xq,
    float* __restrict__ out) {
  __shared__ uint32_t xT[32][128];
  __shared__ uint32_t eT2[32][128];

  const int n0 = blockIdx.x * 128;
  const int b0 = blockIdx.y * 128;
  const int tid = threadIdx.x;
  const int tx = tid & 15;
  const int ty = tid >> 4;
  const int s_row = tid >> 1;
  const int s_half = tid & 1;

  uint32_t acc[8][8];
#pragma unroll
  for (int i = 0; i < 8; ++i)
#pragma unroll
    for (int j = 0; j < 8; ++j) acc[i][j] = 0u;

  for (int d0 = 0; d0 < DIM; d0 += 128) {
    {
      const uint4* src =
          (const uint4*)&xq[(size_t)(b0 + s_row) * KROW + d0 / 4 + s_half * 16];
#pragma unroll
      for (int q = 0; q < 4; ++q) {
        uint4 v = src[q];
        const int k = s_half * 16 + q * 4;
        xT[k + 0][s_row] = v.x;
        xT[k + 1][s_row] = v.y;
        xT[k + 2][s_row] = v.z;
        xT[k + 3][s_row] = v.w;
      }
    }
    {
      const float4* src =
          (const float4*)&ent[(size_t)(n0 + s_row) * DIM + d0 + s_half * 64];
#pragma unroll
      for (int q = 0; q < 16; ++q) {
        float4 v = src[q];
        eT2[s_half * 16 + q][s_row] = quant4(v.x, v.y, v.z, v.w);
      }
    }
    __syncthreads();

#pragma unroll 2
    for (int k = 0; k < 32; ++k) {
      uint32_t xw[8], ew[8];
      *(uint4*)&xw[0] = *(const uint4*)&xT[k][ty * 4];
      *(uint4*)&xw[4] = *(const uint4*)&xT[k][64 + ty * 4];
      *(uint4*)&ew[0] = *(const uint4*)&eT2[k][tx * 4];
      *(uint4*)&ew[4] = *(const uint4*)&eT2[k][64 + tx * 4];
#pragma unroll
      for (int i = 0; i < 8; ++i)
#pragma unroll
        for (int j = 0; j < 8; ++j) acc[i][j] = SAD(xw[i], ew[j], acc[i][j]);
    }
    __syncthreads();
  }

#pragma unroll
  for (int i = 0; i < 8; ++i) {
    const int b = b0 + ((i & 4) << 4) + ty * 4 + (i & 3);
    float* dst = &out[(size_t)b * NE + n0];
    vf4 o0, o1;
    o0.x = (float)acc[i][0] * NINV;
    o0.y = (float)acc[i][1] * NINV;
    o0.z = (float)acc[i][2] * NINV;
    o0.w = (float)acc[i][3] * NINV;
    o1.x = (float)acc[i][4] * NINV;
    o1.y = (float)acc[i][5] * NINV;
    o1.z = (float)acc[i][6] * NINV;
    o1.w = (float)acc[i][7] * NINV;
    __builtin_nontemporal_store(o0, (vf4*)&dst[tx * 4]);
    __builtin_nontemporal_store(o1, (vf4*)&dst[64 + tx * 4]);
  }
}

extern "C" void kernel_launch(void* const* d_in, const int* in_sizes, int n_in,
                              void* d_out, int out_size, void* d_ws,
                              size_t ws_size, hipStream_t stream) {
  const float* ent = (const float*)d_in[0];
  const float* rel = (const float*)d_in[1];
  const int* h_idx = (const int*)d_in[2];
  const int* r_idx = (const int*)d_in[3];
  float* out = (float*)d_out;

  uint32_t* xq = (uint32_t*)d_ws;
  uint32_t* eq = (uint32_t*)((char*)d_ws + XQ_BYTES);

  if (ws_size >= XQ_BYTES + EQ_BYTES) {
    make_xqT_kernel<<<NB, 64, 0, stream>>>(ent, rel, h_idx, r_idx, xq);
    quant_entT_kernel<<<NTILE, 256, 0, stream>>>(ent, eq);
    dim3 grid(NE / 128, NB / 256);
    transe_sad_sgpr_kernel<<<grid, 512, 0, stream>>>(eq, xq, out);
  } else {
    make_xq_kernel<<<NB, 64, 0, stream>>>(ent, rel, h_idx, r_idx, xq);
    dim3 grid(NE / 128, NB / 128);
    transe_sad_f32_kernel<<<grid, 256, 0, stream>>>(ent, xq, out);
  }
}

// Round 12
// 165.104 us; speedup vs baseline: 1.1365x; 1.1365x over previous
//
#include <hip/hip_runtime.h>
#include <stdint.h>

#define NE 102400
#define DIM 256
#define NB 512
#define KROW (DIM / 4)   // 64 packed u32 per row
#define NTILE (NE / 128) // 800 entity tiles

#define SQ 384.0f
#define NINV (-1.0f / 384.0f)

#define XQ_BYTES ((size_t)NB * KROW * 4)        // 128 KiB
#define EQ_BYTES ((size_t)NE * KROW * 4)        // 25 MiB

typedef float vf4 __attribute__((ext_vector_type(4)));
typedef float vf2 __attribute__((ext_vector_type(2)));

#if __has_builtin(__builtin_amdgcn_sad_u8)
#define SAD(a, b, c) __builtin_amdgcn_sad_u8((a), (b), (c))
#else
static __device__ __forceinline__ uint32_t SAD(uint32_t a, uint32_t b,
                                               uint32_t c) {
  asm("v_sad_u8 %0, %1, %2, %0" : "+v"(c) : "v"(a), "v"(b));
  return c;
}
#endif

static __device__ __forceinline__ uint32_t quant4(float a, float b, float c,
                                                  float d) {
  uint32_t q = 0;
  asm("v_cvt_pk_u8_f32 %0, %1, 0, %0" : "+v"(q) : "v"(fmaf(a, SQ, 128.5f)));
  asm("v_cvt_pk_u8_f32 %0, %1, 1, %0" : "+v"(q) : "v"(fmaf(b, SQ, 128.5f)));
  asm("v_cvt_pk_u8_f32 %0, %1, 2, %0" : "+v"(q) : "v"(fmaf(c, SQ, 128.5f)));
  asm("v_cvt_pk_u8_f32 %0, %1, 3, %0" : "+v"(q) : "v"(fmaf(d, SQ, 128.5f)));
  return q;
}

// ---- pre-passes ---------------------------------------------------------

// xqT[k][b] = quantized (ent[h[b]] + rel[r[b]]) dims 4k..4k+3 (k-major).
__global__ __launch_bounds__(64) void make_xqT_kernel(
    const float* __restrict__ ent, const float* __restrict__ rel,
    const int* __restrict__ h_idx, const int* __restrict__ r_idx,
    uint32_t* __restrict__ xqT) {
  const int b = blockIdx.x;
  const int t = threadIdx.x;  // = k
  const float4 e = *(const float4*)&ent[(size_t)h_idx[b] * DIM + t * 4];
  const float4 r = *(const float4*)&rel[(size_t)r_idx[b] * DIM + t * 4];
  xqT[(size_t)t * NB + b] = quant4(e.x + r.x, e.y + r.y, e.z + r.z, e.w + r.w);
}

// eqT[tile][k][c] = quantized ent[tile*128+c] dims 4k..4k+3.
__global__ __launch_bounds__(256) void quant_entT_kernel(
    const float* __restrict__ ent, uint32_t* __restrict__ eqT) {
  const int t0 = blockIdx.x;
  const int r = threadIdx.x >> 1;       // entity row in tile
  const int h = threadIdx.x & 1;        // dim half
  const float* src = &ent[((size_t)t0 * 128 + r) * DIM + h * 128];
  uint32_t* dst = &eqT[(size_t)t0 * (KROW * 128) + (size_t)h * 32 * 128 + r];
#pragma unroll
  for (int q = 0; q < 32; ++q) {
    const float4 v = *(const float4*)&src[q * 4];
    dst[q * 128] = quant4(v.x, v.y, v.z, v.w);
  }
}

// ---- main kernel --------------------------------------------------------
// out[b][n] = -sum_d |x[b][d] - ent[n][d]| via u8 SAD.
// 512 threads = 8 waves. Wave w: 32 uniform batch rows (x via scalar loads,
// SGPR src, double-buffered across k) x 128 entity cols (lane l: cols
// 2l,2l+1 from LDS b64, prefetched one k ahead). e-slab staged once.
__global__ __launch_bounds__(512, 2) void transe_sad_pipe_kernel(
    const uint32_t* __restrict__ eqT, const uint32_t* __restrict__ xqT,
    float* __restrict__ out) {
  __shared__ __align__(16) uint32_t eT[KROW * 128];  // 32 KiB

  const int tid = threadIdx.x;
  const int lane = tid & 63;
  const int wid = __builtin_amdgcn_readfirstlane(tid >> 6);  // 0..7, uniform
  const int n0 = blockIdx.x * 128;
  const int brow = blockIdx.y * 256 + wid * 32;              // uniform

  // ---- stage e-slab once: contiguous 32 KiB memcpy ----
  {
    const uint4* esrc = (const uint4*)(eqT + (size_t)blockIdx.x * (KROW * 128));
    uint4* edst = (uint4*)eT;
#pragma unroll
    for (int p = 0; p < 4; ++p) edst[p * 512 + tid] = esrc[p * 512 + tid];
  }

  uint32_t acc[32][2];
#pragma unroll
  for (int i = 0; i < 32; ++i) {
    acc[i][0] = 0u;
    acc[i][1] = 0u;
  }

  __syncthreads();

  const uint32_t* xrow = xqT + brow;  // uniform pointer

  // ---- prologue: prefetch k=0 ----
  uint2 ev = *(const uint2*)&eT[lane * 2];
  uint32_t sx[32];
#pragma unroll
  for (int i = 0; i < 32; ++i) sx[i] = xrow[i];  // uniform -> s_load

  // ---- pipelined k-loop: prefetch k+1 before SADs of k ----
#pragma unroll 2
  for (int k = 0; k < KROW - 1; ++k) {
    const uint2 evn = *(const uint2*)&eT[(k + 1) * 128 + lane * 2];
    const uint32_t* xp = xrow + (size_t)(k + 1) * NB;  // uniform
    uint32_t sxn[32];
#pragma unroll
    for (int i = 0; i < 32; ++i) sxn[i] = xp[i];       // s_load, no wait yet
#pragma unroll
    for (int i = 0; i < 32; ++i) {
      acc[i][0] = SAD(sx[i], ev.x, acc[i][0]);
      acc[i][1] = SAD(sx[i], ev.y, acc[i][1]);
    }
    ev = evn;
#pragma unroll
    for (int i = 0; i < 32; ++i) sx[i] = sxn[i];       // s_mov rotate
  }
  // ---- epilogue k = KROW-1 ----
#pragma unroll
  for (int i = 0; i < 32; ++i) {
    acc[i][0] = SAD(sx[i], ev.x, acc[i][0]);
    acc[i][1] = SAD(sx[i], ev.y, acc[i][1]);
  }

  // ---- out = -acc/384, non-temporal float2 stores ----
#pragma unroll
  for (int i = 0; i < 32; ++i) {
    float* dst = &out[(size_t)(brow + i) * NE + n0 + lane * 2];
    vf2 o;
    o.x = (float)acc[i][0] * NINV;
    o.y = (float)acc[i][1] * NINV;
    __builtin_nontemporal_store(o, (vf2*)dst);
  }
}

// ---- fallback path (ws too small): row-major xq + in-kernel e-quant ----

__global__ __launch_bounds__(64) void make_xq_kernel(
    const float* __restrict__ ent, const float* __restrict__ rel,
    const int* __restrict__ h_idx, const int* __restrict__ r_idx,
    uint32_t* __restrict__ xq) {
  const int b = blockIdx.x;
  const int t = threadIdx.x;
  const float4 e = *(const float4*)&ent[(size_t)h_idx[b] * DIM + t * 4];
  const float4 r = *(const float4*)&rel[(size_t)r_idx[b] * DIM + t * 4];
  xq[(size_t)b * KROW + t] = quant4(e.x + r.x, e.y + r.y, e.z + r.z, e.w + r.w);
}

__global__ __launch_bounds__(256) void transe_sad_f32_kernel(
    const float* __restrict__ ent, const uint32_t* __restrict__ xq,
    float* __restrict__ out) {
  __shared__ uint32_t xT[32][128];
  __shared__ uint32_t eT2[32][128];

  const int n0 = blockIdx.x * 128;
  const int b0 = blockIdx.y * 128;
  const int tid = threadIdx.x;
  const int tx = tid & 15;
  const int ty = tid >> 4;
  const int s_row = tid >> 1;
  const int s_half = tid & 1;

  uint32_t acc[8][8];
#pragma unroll
  for (int i = 0; i < 8; ++i)
#pragma unroll
    for (int j = 0; j < 8; ++j) acc[i][j] = 0u;

  for (int d0 = 0; d0 < DIM; d0 += 128) {
    {
      const uint4* src =
          (const uint4*)&xq[(size_t)(b0 + s_row) * KROW + d0 / 4 + s_half * 16];
#pragma unroll
      for (int q = 0; q < 4; ++q) {
        uint4 v = src[q];
        const int k = s_half * 16 + q * 4;
        xT[k + 0][s_row] = v.x;
        xT[k + 1][s_row] = v.y;
        xT[k + 2][s_row] = v.z;
        xT[k + 3][s_row] = v.w;
      }
    }
    {
      const float4* src =
          (const float4*)&ent[(size_t)(n0 + s_row) * DIM + d0 + s_half * 64];
#pragma unroll
      for (int q = 0; q < 16; ++q) {
        float4 v = src[q];
        eT2[s_half * 16 + q][s_row] = quant4(v.x, v.y, v.z, v.w);
      }
    }
    __syncthreads();

#pragma unroll 2
    for (int k = 0; k < 32; ++k) {
      uint32_t xw[8], ew[8];
      *(uint4*)&xw[0] = *(const uint4*)&xT[k][ty * 4];
      *(uint4*)&xw[4] = *(const uint4*)&xT[k][64 + ty * 4];
      *(uint4*)&ew[0] = *(const uint4*)&eT2[k][tx * 4];
      *(uint4*)&ew[4] = *(const uint4*)&eT2[k][64 + tx * 4];
#pragma unroll
      for (int i = 0; i < 8; ++i)
#pragma unroll
        for (int j = 0; j < 8; ++j) acc[i][j] = SAD(xw[i], ew[j], acc[i][j]);
    }
    __syncthreads();
  }

#pragma unroll
  for (int i = 0; i < 8; ++i) {
    const int b = b0 + ((i & 4) << 4) + ty * 4 + (i & 3);
    float* dst = &out[(size_t)b * NE + n0];
    vf4 o0, o1;
    o0.x = (float)acc[i][0] * NINV;
    o0.y = (float)acc[i][1] * NINV;
    o0.z = (float)acc[i][2] * NINV;
    o0.w = (float)acc[i][3] * NINV;
    o1.x = (float)acc[i][4] * NINV;
    o1.y = (float)acc[i][5] * NINV;
    o1.z = (float)acc[i][6] * NINV;
    o1.w = (float)acc[i][7] * NINV;
    __builtin_nontemporal_store(o0, (vf4*)&dst[tx * 4]);
    __builtin_nontemporal_store(o1, (vf4*)&dst[64 + tx * 4]);
  }
}

extern "C" void kernel_launch(void* const* d_in, const int* in_sizes, int n_in,
                              void* d_out, int out_size, void* d_ws,
                              size_t ws_size, hipStream_t stream) {
  const float* ent = (const float*)d_in[0];
  const float* rel = (const float*)d_in[1];
  const int* h_idx = (const int*)d_in[2];
  const int* r_idx = (const int*)d_in[3];
  float* out = (float*)d_out;

  uint32_t* xq = (uint32_t*)d_ws;
  uint32_t* eq = (uint32_t*)((char*)d_ws + XQ_BYTES);

  if (ws_size >= XQ_BYTES + EQ_BYTES) {
    make_xqT_kernel<<<NB, 64, 0, stream>>>(ent, rel, h_idx, r_idx, xq);
    quant_entT_kernel<<<NTILE, 256, 0, stream>>>(ent, eq);
    dim3 grid(NE / 128, NB / 256);
    transe_sad_pipe_kernel<<<grid, 512, 0, stream>>>(eq, xq, out);
  } else {
    make_xq_kernel<<<NB, 64, 0, stream>>>(ent, rel, h_idx, r_idx, xq);
    dim3 grid(NE / 128, NB / 128);
    transe_sad_f32_kernel<<<grid, 256, 0, stream>>>(ent, xq, out);
  }
}

// Round 13
// 148.415 us; speedup vs baseline: 1.2643x; 1.1124x over previous
//
#include <hip/hip_runtime.h>
#include <stdint.h>

#define NE 102400
#define DIM 256
#define NB 512
#define KROW (DIM / 4)   // 64 packed u32 per row
#define NTILE (NE / 128) // 800 entity tiles

#define SQ 384.0f
#define NINV (-1.0f / 384.0f)

#define XQ_BYTES ((size_t)NB * KROW * 4)        // 128 KiB
#define EQ_BYTES ((size_t)NE * KROW * 4)        // 25 MiB

typedef float vf4 __attribute__((ext_vector_type(4)));

#if __has_builtin(__builtin_amdgcn_sad_u8)
#define SAD(a, b, c) __builtin_amdgcn_sad_u8((a), (b), (c))
#else
static __device__ __forceinline__ uint32_t SAD(uint32_t a, uint32_t b,
                                               uint32_t c) {
  asm("v_sad_u8 %0, %1, %2, %0" : "+v"(c) : "v"(a), "v"(b));
  return c;
}
#endif

static __device__ __forceinline__ uint32_t quant4(float a, float b, float c,
                                                  float d) {
  uint32_t q = 0;
  asm("v_cvt_pk_u8_f32 %0, %1, 0, %0" : "+v"(q) : "v"(fmaf(a, SQ, 128.5f)));
  asm("v_cvt_pk_u8_f32 %0, %1, 1, %0" : "+v"(q) : "v"(fmaf(b, SQ, 128.5f)));
  asm("v_cvt_pk_u8_f32 %0, %1, 2, %0" : "+v"(q) : "v"(fmaf(c, SQ, 128.5f)));
  asm("v_cvt_pk_u8_f32 %0, %1, 3, %0" : "+v"(q) : "v"(fmaf(d, SQ, 128.5f)));
  return q;
}

// ---- pre-passes ---------------------------------------------------------

// xqT[k][b] = quantized (ent[h[b]] + rel[r[b]]) dims 4k..4k+3 (k-major).
__global__ __launch_bounds__(64) void make_xqT_kernel(
    const float* __restrict__ ent, const float* __restrict__ rel,
    const int* __restrict__ h_idx, const int* __restrict__ r_idx,
    uint32_t* __restrict__ xqT) {
  const int b = blockIdx.x;
  const int t = threadIdx.x;  // = k
  const float4 e = *(const float4*)&ent[(size_t)h_idx[b] * DIM + t * 4];
  const float4 r = *(const float4*)&rel[(size_t)r_idx[b] * DIM + t * 4];
  xqT[(size_t)t * NB + b] = quant4(e.x + r.x, e.y + r.y, e.z + r.z, e.w + r.w);
}

// eqT[tile][k][c] = quantized ent[tile*128+c] dims 4k..4k+3 (k-major slab).
__global__ __launch_bounds__(256) void quant_entT_kernel(
    const float* __restrict__ ent, uint32_t* __restrict__ eqT) {
  const int t0 = blockIdx.x;
  const int r = threadIdx.x >> 1;       // entity row in tile
  const int h = threadIdx.x & 1;        // dim half
  const float* src = &ent[((size_t)t0 * 128 + r) * DIM + h * 128];
  uint32_t* dst = &eqT[(size_t)t0 * (KROW * 128) + (size_t)h * 32 * 128 + r];
#pragma unroll
  for (int q = 0; q < 32; ++q) {
    const float4 v = *(const float4*)&src[q * 4];
    dst[q * 128] = quant4(v.x, v.y, v.z, v.w);
  }
}

// ---- main kernel --------------------------------------------------------
// out[b][n] = -sum_d |x[b][d] - ent[n][d]| via u8 SAD.
// 128x128 tile / 256 threads / 8x8 acc (the R6-proven shape). k-major
// staging: e-slab (64 k, 32 KiB) staged ONCE with b128 writes; x staged
// per 32-k stage, stage-1 loads issued before stage-0 compute (T14).
__global__ __launch_bounds__(256, 3) void transe_sad_v2_kernel(
    const uint32_t* __restrict__ eqT, const uint32_t* __restrict__ xqT,
    float* __restrict__ out) {
  __shared__ __align__(16) uint32_t eT[KROW * 128];  // 32 KiB
  __shared__ __align__(16) uint32_t xT[32 * 128];    // 16 KiB

  const int tid = threadIdx.x;
  const int tx = tid & 15;
  const int ty = tid >> 4;
  const int n0 = blockIdx.x * 128;
  const int b0 = blockIdx.y * 128;

  // ---- issue e-slab + x stage-0 loads (all coalesced uint4) ----
  const uint32_t* eslab = eqT + (size_t)blockIdx.x * (KROW * 128);
  uint4 ereg[8];
#pragma unroll
  for (int p = 0; p < 8; ++p)
    ereg[p] = *(const uint4*)&eslab[p * 1024 + tid * 4];

  uint4 xreg[4];
#pragma unroll
  for (int p = 0; p < 4; ++p) {
    const int d = p * 1024 + tid * 4;
    xreg[p] = *(const uint4*)&xqT[(size_t)(d >> 7) * NB + b0 + (d & 127)];
  }

  // ---- write e-slab + x0 to LDS (b128, conflict-free) ----
#pragma unroll
  for (int p = 0; p < 8; ++p) *(uint4*)&eT[p * 1024 + tid * 4] = ereg[p];
#pragma unroll
  for (int p = 0; p < 4; ++p) *(uint4*)&xT[p * 1024 + tid * 4] = xreg[p];

  // ---- issue x stage-1 loads EARLY; held in regs across stage-0 ----
#pragma unroll
  for (int p = 0; p < 4; ++p) {
    const int d = p * 1024 + tid * 4;
    xreg[p] =
        *(const uint4*)&xqT[(size_t)(32 + (d >> 7)) * NB + b0 + (d & 127)];
  }

  uint32_t acc[8][8];
#pragma unroll
  for (int i = 0; i < 8; ++i)
#pragma unroll
    for (int j = 0; j < 8; ++j) acc[i][j] = 0u;

  __syncthreads();

  // ---- stage 0: k = 0..31 ----
#pragma unroll 2
  for (int k = 0; k < 32; ++k) {
    uint32_t xw[8], ew[8];
    *(uint4*)&xw[0] = *(const uint4*)&xT[k * 128 + ty * 4];
    *(uint4*)&xw[4] = *(const uint4*)&xT[k * 128 + 64 + ty * 4];
    *(uint4*)&ew[0] = *(const uint4*)&eT[k * 128 + tx * 4];
    *(uint4*)&ew[4] = *(const uint4*)&eT[k * 128 + 64 + tx * 4];
#pragma unroll
    for (int i = 0; i < 8; ++i)
#pragma unroll
      for (int j = 0; j < 8; ++j) acc[i][j] = SAD(xw[i], ew[j], acc[i][j]);
  }

  __syncthreads();
  // ---- write x1 (loads long since landed) ----
#pragma unroll
  for (int p = 0; p < 4; ++p) *(uint4*)&xT[p * 1024 + tid * 4] = xreg[p];
  __syncthreads();

  // ---- stage 1: k = 32..63 ----
#pragma unroll 2
  for (int k = 0; k < 32; ++k) {
    uint32_t xw[8], ew[8];
    *(uint4*)&xw[0] = *(const uint4*)&xT[k * 128 + ty * 4];
    *(uint4*)&xw[4] = *(const uint4*)&xT[k * 128 + 64 + ty * 4];
    *(uint4*)&ew[0] = *(const uint4*)&eT[(32 + k) * 128 + tx * 4];
    *(uint4*)&ew[4] = *(const uint4*)&eT[(32 + k) * 128 + 64 + tx * 4];
#pragma unroll
    for (int i = 0; i < 8; ++i)
#pragma unroll
      for (int j = 0; j < 8; ++j) acc[i][j] = SAD(xw[i], ew[j], acc[i][j]);
  }

  // ---- epilogue: out = -acc/384, non-temporal stores ----
#pragma unroll
  for (int i = 0; i < 8; ++i) {
    const int b = b0 + ((i & 4) << 4) + ty * 4 + (i & 3);
    float* dst = &out[(size_t)b * NE + n0];
    vf4 o0, o1;
    o0.x = (float)acc[i][0] * NINV;
    o0.y = (float)acc[i][1] * NINV;
    o0.z = (float)acc[i][2] * NINV;
    o0.w = (float)acc[i][3] * NINV;
    o1.x = (float)acc[i][4] * NINV;
    o1.y = (float)acc[i][5] * NINV;
    o1.z = (float)acc[i][6] * NINV;
    o1.w = (float)acc[i][7] * NINV;
    __builtin_nontemporal_store(o0, (vf4*)&dst[tx * 4]);
    __builtin_nontemporal_store(o1, (vf4*)&dst[64 + tx * 4]);
  }
}

// ---- fallback path (ws too small): row-major xq + in-kernel e-quant ----

__global__ __launch_bounds__(64) void make_xq_kernel(
    const float* __restrict__ ent, const float* __restrict__ rel,
    const int* __restrict__ h_idx, const int* __restrict__ r_idx,
    uint32_t* __restrict__ xq) {
  const int b = blockIdx.x;
  const int t = threadIdx.x;
  const float4 e = *(const float4*)&ent[(size_t)h_idx[b] * DIM + t * 4];
  const float4 r = *(const float4*)&rel[(size_t)r_idx[b] * DIM + t * 4];
  xq[(size_t)b * KROW + t] = quant4(e.x + r.x, e.y + r.y, e.z + r.z, e.w + r.w);
}

__global__ __launch_bounds__(256) void transe_sad_f32_kernel(
    const float* __restrict__ ent, const uint32_t* __restrict__ xq,
    float* __restrict__ out) {
  __shared__ uint32_t xTl[32][128];
  __shared__ uint32_t eTl[32][128];

  const int n0 = blockIdx.x * 128;
  const int b0 = blockIdx.y * 128;
  const int tid = threadIdx.x;
  const int tx = tid & 15;
  const int ty = tid >> 4;
  const int s_row = tid >> 1;
  const int s_half = tid & 1;

  uint32_t acc[8][8];
#pragma unroll
  for (int i = 0; i < 8; ++i)
#pragma unroll
    for (int j = 0; j < 8; ++j) acc[i][j] = 0u;

  for (int d0 = 0; d0 < DIM; d0 += 128) {
    {
      const uint4* src =
          (const uint4*)&xq[(size_t)(b0 + s_row) * KROW + d0 / 4 + s_half * 16];
#pragma unroll
      for (int q = 0; q < 4; ++q) {
        uint4 v = src[q];
        const int k = s_half * 16 + q * 4;
        xTl[k + 0][s_row] = v.x;
        xTl[k + 1][s_row] = v.y;
        xTl[k + 2][s_row] = v.z;
        xTl[k + 3][s_row] = v.w;
      }
    }
    {
      const float4* src =
          (const float4*)&ent[(size_t)(n0 + s_row) * DIM + d0 + s_half * 64];
#pragma unroll
      for (int q = 0; q < 16; ++q) {
        float4 v = src[q];
        eTl[s_half * 16 + q][s_row] = quant4(v.x, v.y, v.z, v.w);
      }
    }
    __syncthreads();

#pragma unroll 2
    for (int k = 0; k < 32; ++k) {
      uint32_t xw[8], ew[8];
      *(uint4*)&xw[0] = *(const uint4*)&xTl[k][ty * 4];
      *(uint4*)&xw[4] = *(const uint4*)&xTl[k][64 + ty * 4];
      *(uint4*)&ew[0] = *(const uint4*)&eTl[k][tx * 4];
      *(uint4*)&ew[4] = *(const uint4*)&eTl[k][64 + tx * 4];
#pragma unroll
      for (int i = 0; i < 8; ++i)
#pragma unroll
        for (int j = 0; j < 8; ++j) acc[i][j] = SAD(xw[i], ew[j], acc[i][j]);
    }
    __syncthreads();
  }

#pragma unroll
  for (int i = 0; i < 8; ++i) {
    const int b = b0 + ((i & 4) << 4) + ty * 4 + (i & 3);
    float* dst = &out[(size_t)b * NE + n0];
    vf4 o0, o1;
    o0.x = (float)acc[i][0] * NINV;
    o0.y = (float)acc[i][1] * NINV;
    o0.z = (float)acc[i][2] * NINV;
    o0.w = (float)acc[i][3] * NINV;
    o1.x = (float)acc[i][4] * NINV;
    o1.y = (float)acc[i][5] * NINV;
    o1.z = (float)acc[i][6] * NINV;
    o1.w = (float)acc[i][7] * NINV;
    __builtin_nontemporal_store(o0, (vf4*)&dst[tx * 4]);
    __builtin_nontemporal_store(o1, (vf4*)&dst[64 + tx * 4]);
  }
}

extern "C" void kernel_launch(void* const* d_in, const int* in_sizes, int n_in,
                              void* d_out, int out_size, void* d_ws,
                              size_t ws_size, hipStream_t stream) {
  const float* ent = (const float*)d_in[0];
  const float* rel = (const float*)d_in[1];
  const int* h_idx = (const int*)d_in[2];
  const int* r_idx = (const int*)d_in[3];
  float* out = (float*)d_out;

  uint32_t* xq = (uint32_t*)d_ws;
  uint32_t* eq = (uint32_t*)((char*)d_ws + XQ_BYTES);

  if (ws_size >= XQ_BYTES + EQ_BYTES) {
    make_xqT_kernel<<<NB, 64, 0, stream>>>(ent, rel, h_idx, r_idx, xq);
    quant_entT_kernel<<<NTILE, 256, 0, stream>>>(ent, eq);
    dim3 grid(NE / 128, NB / 128);
    transe_sad_v2_kernel<<<grid, 256, 0, stream>>>(eq, xq, out);
  } else {
    make_xq_kernel<<<NB, 64, 0, stream>>>(ent, rel, h_idx, r_idx, xq);
    dim3 grid(NE / 128, NB / 128);
    transe_sad_f32_kernel<<<grid, 256, 0, stream>>>(ent, xq, out);
  }
}